// Round 6
// baseline (309.100 us; speedup 1.0000x reference)
//
#include <hip/hip_runtime.h>
#include <math.h>

#define CI 64
#define HH 256
#define WW 256
#define SS (HH*WW)

typedef __attribute__((ext_vector_type(8))) short bf16x8;
typedef __attribute__((ext_vector_type(4))) float f32x4;

// workspace: num [N][1024] (h*256+k*16+v) -> 4096 ; den [N][64] -> 256
__global__ void k_zero(float* __restrict__ ws) {
  int i = blockIdx.x * 256 + threadIdx.x;
  if (i < 4352) ws[i] = 0.f;
}

__device__ __forceinline__ ushort f2bf(float f) {
  unsigned u = __float_as_uint(f);
  u += 0x7FFF + ((u >> 16) & 1);          // round-to-nearest-even
  return (ushort)(u >> 16);
}
__device__ __forceinline__ float bf2f(ushort h) { return __uint_as_float(((unsigned)h) << 16); }
__device__ __forceinline__ void split(float x, ushort& h, ushort& l) {
  h = f2bf(x); l = f2bf(x - bf2f(h));
}

// swizzled tiles: 64 rows x 64 ushort cols; 8-elem chunk index XOR'd with row&7
__device__ __forceinline__ bf16x8 ld8(const ushort* t, int row, int c8) {
  return *reinterpret_cast<const bf16x8*>(t + row * 64 + ((c8 ^ (row & 7)) << 3));
}
__device__ __forceinline__ int swi(int row, int col) {
  return row * 64 + ((((col >> 3) ^ (row & 7)) << 3) | (col & 7));
}

union B8 { bf16x8 v; ushort u[8]; };

// per-wave A-fragments of a 64x64 row-major weight matrix, rows h16..h16+15, hi/lo split
struct WFrag { bf16x8 h[2]; bf16x8 l[2]; };
__device__ __forceinline__ WFrag load_w(const float* __restrict__ W, int h16, int lane) {
  WFrag f;
  int m = lane & 15, q = lane >> 4;
#pragma unroll
  for (int ks = 0; ks < 2; ks++) {
    const float* p = W + (size_t)(h16 + m) * 64 + ks * 32 + q * 8;
    float4 f0 = *(const float4*)p, f1 = *(const float4*)(p + 4);
    float vals[8] = {f0.x, f0.y, f0.z, f0.w, f1.x, f1.y, f1.z, f1.w};
    B8 hh, ll;
#pragma unroll
    for (int j = 0; j < 8; j++) { ushort a, b; split(vals[j], a, b); hh.u[j] = a; ll.u[j] = b; }
    f.h[ks] = hh.v; f.l[ks] = ll.v;
  }
  return f;
}

// wave GEMM: D[16 rows][64 px] = W(16 chans) * T, T px-row-major tile
__device__ __forceinline__ void gemm_wave(const WFrag& w, const ushort* Th, const ushort* Tl,
                                          int lane, f32x4 acc[4]) {
  int m = lane & 15, q = lane >> 4;
#pragma unroll
  for (int nt = 0; nt < 4; nt++) {
#pragma unroll
    for (int ks = 0; ks < 2; ks++) {
      bf16x8 bh = ld8(Th, nt * 16 + m, ks * 4 + q);
      bf16x8 bl = ld8(Tl, nt * 16 + m, ks * 4 + q);
      acc[nt] = __builtin_amdgcn_mfma_f32_16x16x32_bf16(w.h[ks], bh, acc[nt], 0, 0, 0);
      acc[nt] = __builtin_amdgcn_mfma_f32_16x16x32_bf16(w.h[ks], bl, acc[nt], 0, 0, 0);
      acc[nt] = __builtin_amdgcn_mfma_f32_16x16x32_bf16(w.l[ks], bh, acc[nt], 0, 0, 0);
    }
  }
}

__device__ __forceinline__ void bilin_params(float py, float px, float w[4], int a[4]) {
  float y0f = floorf(py), x0f = floorf(px);
  float wy1 = py - y0f, wy0 = 1.f - wy1;
  float wx1 = px - x0f, wx0 = 1.f - wx1;
  int iy0 = (int)y0f, ix0 = (int)x0f;
  int iy1 = iy0 + 1, ix1 = ix0 + 1;
  float vy0 = (iy0 >= 0 && iy0 < HH) ? 1.f : 0.f;
  float vy1 = (iy1 >= 0 && iy1 < HH) ? 1.f : 0.f;
  float vx0 = (ix0 >= 0 && ix0 < WW) ? 1.f : 0.f;
  float vx1 = (ix1 >= 0 && ix1 < WW) ? 1.f : 0.f;
  int cy0 = min(max(iy0, 0), HH - 1), cy1 = min(max(iy1, 0), HH - 1);
  int cx0 = min(max(ix0, 0), WW - 1), cx1 = min(max(ix1, 0), WW - 1);
  w[0] = wy0 * wx0 * vy0 * vx0;
  w[1] = wy0 * wx1 * vy0 * vx1;
  w[2] = wy1 * wx0 * vy1 * vx0;
  w[3] = wy1 * wx1 * vy1 * vx1;
  a[0] = cy0 * WW + cx0;  a[1] = cy0 * WW + cx1;
  a[2] = cy1 * WW + cx0;  a[3] = cy1 * WW + cx1;
}

// sample 16 channels (this wave's block) of pixel `pix` -> bf16 hi/lo px-row tile
__device__ __forceinline__ void sample16(const float* __restrict__ Xb,
                                         const float* __restrict__ pw,
                                         const int* __restrict__ pa,
                                         ushort* __restrict__ Sh, ushort* __restrict__ Sl,
                                         int pix, int cg) {
  float w0 = pw[0 * 64 + pix], w1 = pw[1 * 64 + pix], w2 = pw[2 * 64 + pix], w3 = pw[3 * 64 + pix];
  int a0 = pa[0 * 64 + pix], a1 = pa[1 * 64 + pix], a2 = pa[2 * 64 + pix], a3 = pa[3 * 64 + pix];
#pragma unroll 2
  for (int half = 0; half < 2; half++) {
    B8 hh, ll;
#pragma unroll
    for (int j = 0; j < 8; j++) {
      const float* Xc = Xb + (size_t)(half * 8 + j) * SS;
      float v = w0 * Xc[a0] + w1 * Xc[a1] + w2 * Xc[a2] + w3 * Xc[a3];
      ushort a, b; split(v, a, b); hh.u[j] = a; ll.u[j] = b;
    }
    int idx = pix * 64 + ((((cg * 2 + half) ^ (pix & 7))) << 3);
    *reinterpret_cast<bf16x8*>(Sh + idx) = hh.v;
    *reinterpret_cast<bf16x8*>(Sl + idx) = ll.v;
  }
}

// ---------------- K1: context accumulation (one row / block, 4-tile loop) ----------------
__global__ __launch_bounds__(256, 4) void k_context(
    const float* __restrict__ x,
    const float* __restrict__ kow, const float* __restrict__ kob,
    const float* __restrict__ kw,
    const float* __restrict__ vow, const float* __restrict__ vob,
    const float* __restrict__ vw,
    float* __restrict__ num, float* __restrict__ den) {
  __shared__ ushort Sh[4096], Sl[4096];   // k-sample tile, then E (exp-keys) chan-rows
  __shared__ ushort Vh[4096], Vl[4096];   // v-sample tile, then V-values chan-rows
  __shared__ float red[1024];             // [4 sums][4 cg][64 px]
  __shared__ float pws[512];              // [2 sel][4 tap][64 px]
  __shared__ int   pas[512];

  const int t = threadIdx.x;
  const int bp = ((blockIdx.x & 7) << 7) | (blockIdx.x >> 3);  // XCD-chunked, bijective
  const int yrow = bp & 255, n = bp >> 8;
  const float* xn = x + (size_t)n * CI * SS;
  const int pix = t & 63;                 // lane
  const int cg = t >> 6;                  // wave = head
  const int cgu = __builtin_amdgcn_readfirstlane(cg);
  const int m = pix & 15, q = pix >> 4;
  const float* Xb = xn + (size_t)(cgu * 16) * SS;

  const WFrag wk = load_w(kw, cgu * 16, pix);
  const WFrag wv = load_w(vw, cgu * 16, pix);
  f32x4 cacc = {0, 0, 0, 0};
  float dacc[4] = {0, 0, 0, 0};

  for (int xt = 0; xt < 4; ++xt) {
    const int xb = xt * 64;
    const int s0 = yrow * WW + xb;

    // A: offset partial dots (k and v) -> red
    {
      const float* xc = Xb + s0 + pix;
      float p0 = 0, p1 = 0, p2 = 0, p3 = 0;
#pragma unroll 8
      for (int i = 0; i < 16; i++) {
        float xv = xc[(size_t)i * SS];
        p0 += kow[cgu * 16 + i] * xv;
        p1 += kow[64 + cgu * 16 + i] * xv;
        p2 += vow[cgu * 16 + i] * xv;
        p3 += vow[64 + cgu * 16 + i] * xv;
      }
      red[(0 * 4 + cg) * 64 + pix] = p0;
      red[(1 * 4 + cg) * 64 + pix] = p1;
      red[(2 * 4 + cg) * 64 + pix] = p2;
      red[(3 * 4 + cg) * 64 + pix] = p3;
    }
    __syncthreads();
    // A2: bilinear params (sel 0=k, 1=v)
    if (t < 128) {
      int p = t & 63, sel = t >> 6, qb = sel * 2;
      float oy = red[((qb + 0) * 4 + 0) * 64 + p] + red[((qb + 0) * 4 + 1) * 64 + p] +
                 red[((qb + 0) * 4 + 2) * 64 + p] + red[((qb + 0) * 4 + 3) * 64 + p];
      float ox = red[((qb + 1) * 4 + 0) * 64 + p] + red[((qb + 1) * 4 + 1) * 64 + p] +
                 red[((qb + 1) * 4 + 2) * 64 + p] + red[((qb + 1) * 4 + 3) * 64 + p];
      const float* ob = sel ? vob : kob;
      float py = (float)yrow + oy + ob[0];
      float px = (float)(xb + p) + ox + ob[1];
      float w4[4]; int a4[4];
      bilin_params(py, px, w4, a4);
#pragma unroll
      for (int qq = 0; qq < 4; qq++) { pws[(sel * 4 + qq) * 64 + p] = w4[qq]; pas[(sel * 4 + qq) * 64 + p] = a4[qq]; }
    }
    __syncthreads();
    // C: co-issued k and v gathers -> S, V
    sample16(Xb, pws, pas, Sh, Sl, pix, cg);
    sample16(Xb, pws + 256, pas + 256, Vh, Vl, pix, cg);
    __syncthreads();
    // D: keys GEMM -> exp -> ek regs + den partials; F: values GEMM
    float ek[16];
    f32x4 vacc[4] = {{0,0,0,0},{0,0,0,0},{0,0,0,0},{0,0,0,0}};
    {
      f32x4 acc[4] = {{0,0,0,0},{0,0,0,0},{0,0,0,0},{0,0,0,0}};
      gemm_wave(wk, Sh, Sl, pix, acc);
      gemm_wave(wv, Vh, Vl, pix, vacc);
#pragma unroll
      for (int nt = 0; nt < 4; nt++)
#pragma unroll
        for (int r = 0; r < 4; r++) ek[nt * 4 + r] = __expf(acc[nt][r]);
#pragma unroll
      for (int r = 0; r < 4; r++) dacc[r] += ek[r] + ek[4 + r] + ek[8 + r] + ek[12 + r];
    }
    __syncthreads();   // all S/V reads done
    // F2: commit E -> S-region, V -> V-region (chan-row tiles, hi/lo)
#pragma unroll
    for (int nt = 0; nt < 4; nt++) {
      int px = nt * 16 + m;
#pragma unroll
      for (int r = 0; r < 4; r++) {
        int row = cgu * 16 + q * 4 + r;
        int ix = swi(row, px);
        ushort a, b;
        split(ek[nt * 4 + r], a, b);  Sh[ix] = a; Sl[ix] = b;
        split(vacc[nt][r], a, b);     Vh[ix] = a; Vl[ix] = b;
      }
    }
    __syncthreads();
    // G: ctx += E * V^T per head (K-loop accumulate into cacc); no trailing barrier
    //    (next iter's A/A2 barriers precede the C overwrite of S/V)
#pragma unroll
    for (int ks = 0; ks < 2; ks++) {
      bf16x8 ah = ld8(Sh, cgu * 16 + m, ks * 4 + q);
      bf16x8 al = ld8(Sl, cgu * 16 + m, ks * 4 + q);
      bf16x8 bh = ld8(Vh, cgu * 16 + m, ks * 4 + q);
      bf16x8 bl = ld8(Vl, cgu * 16 + m, ks * 4 + q);
      cacc = __builtin_amdgcn_mfma_f32_16x16x32_bf16(ah, bh, cacc, 0, 0, 0);
      cacc = __builtin_amdgcn_mfma_f32_16x16x32_bf16(ah, bl, cacc, 0, 0, 0);
      cacc = __builtin_amdgcn_mfma_f32_16x16x32_bf16(al, bh, cacc, 0, 0, 0);
    }
  }
  // final: one atomic round per block
  {
    float* nb = num + n * 1024 + cgu * 256;
#pragma unroll
    for (int r = 0; r < 4; r++) atomicAdd(&nb[(q * 4 + r) * 16 + m], cacc[r]);
#pragma unroll
    for (int mask = 1; mask < 16; mask <<= 1)
#pragma unroll
      for (int r = 0; r < 4; r++) dacc[r] += __shfl_xor(dacc[r], mask);
    if (m == 0) {
#pragma unroll
      for (int r = 0; r < 4; r++) atomicAdd(&den[n * 64 + cgu * 16 + q * 4 + r], dacc[r]);
    }
  }
}

// ---------------- K3: query path + output (one row / block, 4-tile loop) ----------------
__global__ __launch_bounds__(256, 4) void k_output(
    const float* __restrict__ x,
    const float* __restrict__ qow, const float* __restrict__ qob,
    const float* __restrict__ qw,
    const float* __restrict__ rw, const float* __restrict__ rb,
    const float* __restrict__ num, const float* __restrict__ den,
    float* __restrict__ out) {
  __shared__ ushort Sh[4096], Sl[4096];   // q-sample tile, then attended tile
  __shared__ ushort Qh[4096], Ql[4096];   // q-softmax tile; first 2KB alias red2
  __shared__ float ctxs[1024];
  __shared__ float pws2[256];
  __shared__ int   pas2[256];
  float* red2 = (float*)Qh;               // [8][64] floats, dead before D writes Q

  const int t = threadIdx.x;
  const int bp = ((blockIdx.x & 7) << 7) | (blockIdx.x >> 3);
  const int yrow = bp & 255, n = bp >> 8;
  const float* xn = x + (size_t)n * CI * SS;
  const int pix = t & 63;
  const int cg = t >> 6;
  const int cgu = __builtin_amdgcn_readfirstlane(cg);
  const int m = pix & 15, q = pix >> 4;
  const float* Xb = xn + (size_t)(cgu * 16) * SS;

  const WFrag wq = load_w(qw, cgu * 16, pix);
  const WFrag wr = load_w(rw, cgu * 16, pix);
  float rbv[4];
#pragma unroll
  for (int r = 0; r < 4; r++) rbv[r] = rb[cgu * 16 + q * 4 + r];

  // ctx normalize -> LDS, then hoist this wave's ctx A-fragment into regs
#pragma unroll
  for (int i = 0; i < 4; i++) {
    int e = t + i * 256;
    ctxs[e] = num[n * 1024 + e] / den[n * 64 + (e >> 4)];
  }
  __syncthreads();
  bf16x8 cah, cal;
  {
    B8 hh, ll;
#pragma unroll
    for (int j = 0; j < 8; j++) {
      float cv = (q < 2) ? ctxs[cgu * 256 + (q * 8 + j) * 16 + m] : 0.f;
      ushort a, b; split(cv, a, b); hh.u[j] = a; ll.u[j] = b;
    }
    cah = hh.v; cal = ll.v;
  }

  for (int xt = 0; xt < 4; ++xt) {
    const int xb = xt * 64;
    const int s0 = yrow * WW + xb;

    // A: q offset partial dots -> red2 (aliases Q; Q's last read was before prev barrier)
    {
      const float* xc = Xb + s0 + pix;
      float p0 = 0, p1 = 0;
#pragma unroll 8
      for (int i = 0; i < 16; i++) {
        float xv = xc[(size_t)i * SS];
        p0 += qow[cgu * 16 + i] * xv;
        p1 += qow[64 + cgu * 16 + i] * xv;
      }
      red2[cg * 64 + pix] = p0;
      red2[(4 + cg) * 64 + pix] = p1;
    }
    __syncthreads();
    // A2
    if (t < 64) {
      float oy = red2[0 * 64 + t] + red2[1 * 64 + t] + red2[2 * 64 + t] + red2[3 * 64 + t];
      float ox = red2[4 * 64 + t] + red2[5 * 64 + t] + red2[6 * 64 + t] + red2[7 * 64 + t];
      float py = (float)yrow + oy + qob[0];
      float px = (float)(xb + t) + ox + qob[1];
      float w4[4]; int a4[4];
      bilin_params(py, px, w4, a4);
#pragma unroll
      for (int qq = 0; qq < 4; qq++) { pws2[qq * 64 + t] = w4[qq]; pas2[qq * 64 + t] = a4[qq]; }
    }
    __syncthreads();
    // C: sample q -> S
    sample16(Xb, pws2, pas2, Sh, Sl, pix, cg);
    __syncthreads();
    // D: queries GEMM + per-(px,head) softmax in regs; write qsm^T -> Q
    {
      f32x4 acc[4] = {{0,0,0,0},{0,0,0,0},{0,0,0,0},{0,0,0,0}};
      gemm_wave(wq, Sh, Sl, pix, acc);
#pragma unroll
      for (int nt = 0; nt < 4; nt++) {
        float mx = fmaxf(fmaxf(acc[nt][0], acc[nt][1]), fmaxf(acc[nt][2], acc[nt][3]));
        mx = fmaxf(mx, __shfl_xor(mx, 16));
        mx = fmaxf(mx, __shfl_xor(mx, 32));
        float e[4]; float ssum = 0.f;
#pragma unroll
        for (int r = 0; r < 4; r++) { e[r] = __expf(acc[nt][r] - mx); ssum += e[r]; }
        ssum += __shfl_xor(ssum, 16);
        ssum += __shfl_xor(ssum, 32);
        float inv = 1.f / ssum;
        int px = nt * 16 + m;
#pragma unroll
        for (int r = 0; r < 4; r++) {
          int ix = swi(px, cgu * 16 + q * 4 + r);
          ushort a, b; split(e[r] * inv, a, b);
          Qh[ix] = a; Ql[ix] = b;
        }
      }
    }
    __syncthreads();   // Q written; S reads done
    // E: attended = ctx^T x qsm -> att regs; write att -> S
    {
      bf16x8 z = {0, 0, 0, 0, 0, 0, 0, 0};
#pragma unroll
      for (int nt = 0; nt < 4; nt++) {
        bf16x8 bh = (q < 2) ? ld8(Qh, nt * 16 + m, cgu * 2 + q) : z;
        bf16x8 bl = (q < 2) ? ld8(Ql, nt * 16 + m, cgu * 2 + q) : z;
        f32x4 c = {0, 0, 0, 0};
        c = __builtin_amdgcn_mfma_f32_16x16x32_bf16(cah, bh, c, 0, 0, 0);
        c = __builtin_amdgcn_mfma_f32_16x16x32_bf16(cah, bl, c, 0, 0, 0);
        c = __builtin_amdgcn_mfma_f32_16x16x32_bf16(cal, bh, c, 0, 0, 0);
        int px = nt * 16 + m;
#pragma unroll
        for (int r = 0; r < 4; r++) {
          int ix = swi(px, cgu * 16 + q * 4 + r);
          ushort a, b; split(c[r], a, b);
          Sh[ix] = a; Sl[ix] = b;
        }
      }
    }
    __syncthreads();   // att written
    // F: output GEMM + bias, store (no trailing barrier; next iter's A/A2 bars cover)
    {
      f32x4 oacc[4] = {{0,0,0,0},{0,0,0,0},{0,0,0,0},{0,0,0,0}};
      gemm_wave(wr, Sh, Sl, pix, oacc);
#pragma unroll
      for (int nt = 0; nt < 4; nt++) {
#pragma unroll
        for (int r = 0; r < 4; r++) {
          int o = cgu * 16 + q * 4 + r;
          out[(size_t)(n * 64 + o) * SS + s0 + nt * 16 + m] = oacc[nt][r] + rbv[r];
        }
      }
    }
  }
}

extern "C" void kernel_launch(void* const* d_in, const int* in_sizes, int n_in,
                              void* d_out, int out_size, void* d_ws, size_t ws_size,
                              hipStream_t stream) {
  const float* x   = (const float*)d_in[0];
  const float* kow = (const float*)d_in[1];
  const float* kob = (const float*)d_in[2];
  const float* kw  = (const float*)d_in[3];
  const float* qow = (const float*)d_in[4];
  const float* qob = (const float*)d_in[5];
  const float* qw  = (const float*)d_in[6];
  const float* vow = (const float*)d_in[7];
  const float* vob = (const float*)d_in[8];
  const float* vw  = (const float*)d_in[9];
  const float* rw  = (const float*)d_in[10];
  const float* rb  = (const float*)d_in[11];
  float* out = (float*)d_out;
  float* wsf = (float*)d_ws;
  float* num = wsf;          // 4096
  float* den = wsf + 4096;   // 256

  hipLaunchKernelGGL(k_zero, dim3(17), dim3(256), 0, stream, wsf);
  hipLaunchKernelGGL(k_context, dim3(1024), dim3(256), 0, stream,
                     x, kow, kob, kw, vow, vob, vw, num, den);
  hipLaunchKernelGGL(k_output, dim3(1024), dim3(256), 0, stream,
                     x, qow, qob, qw, rw, rb, num, den, out);
}

// Round 10
// 294.911 us; speedup vs baseline: 1.0481x; 1.0481x over previous
//
#include <hip/hip_runtime.h>
#include <math.h>

#define CI 64
#define HH 256
#define WW 256
#define SS (HH*WW)

typedef __attribute__((ext_vector_type(8))) short bf16x8;
typedef __attribute__((ext_vector_type(4))) float f32x4;

// workspace: num [N][1024] (h*256+k*16+v) -> 4096 ; den [N][64] -> 256
__global__ void k_zero(float* __restrict__ ws) {
  int i = blockIdx.x * 256 + threadIdx.x;
  if (i < 4352) ws[i] = 0.f;
}

__device__ __forceinline__ ushort f2bf(float f) {
  unsigned u = __float_as_uint(f);
  u += 0x7FFF + ((u >> 16) & 1);          // round-to-nearest-even
  return (ushort)(u >> 16);
}
__device__ __forceinline__ float bf2f(ushort h) { return __uint_as_float(((unsigned)h) << 16); }
__device__ __forceinline__ void split(float x, ushort& h, ushort& l) {
  h = f2bf(x); l = f2bf(x - bf2f(h));
}

// swizzled tiles: 64 rows x 64 ushort cols; chunk (8 elems) index XOR'd with row&7
__device__ __forceinline__ bf16x8 ld8(const ushort* t, int row, int c8) {
  return *reinterpret_cast<const bf16x8*>(t + row * 64 + ((c8 ^ (row & 7)) << 3));
}
__device__ __forceinline__ int swi(int row, int col) {   // scalar element index
  return row * 64 + ((((col >> 3) ^ (row & 7)) << 3) | (col & 7));
}

union B8 { bf16x8 v; ushort u[8]; };

// per-wave A-fragments of a 64x64 row-major weight matrix, rows h16..h16+15, hi/lo split
struct WFrag { bf16x8 h[2]; bf16x8 l[2]; };
__device__ __forceinline__ WFrag load_w(const float* __restrict__ W, int h16, int lane) {
  WFrag f;
  int m = lane & 15, q = lane >> 4;
#pragma unroll
  for (int ks = 0; ks < 2; ks++) {
    const float* p = W + (size_t)(h16 + m) * 64 + ks * 32 + q * 8;
    float4 f0 = *(const float4*)p, f1 = *(const float4*)(p + 4);
    float vals[8] = {f0.x, f0.y, f0.z, f0.w, f1.x, f1.y, f1.z, f1.w};
    B8 hh, ll;
#pragma unroll
    for (int j = 0; j < 8; j++) { ushort a, b; split(vals[j], a, b); hh.u[j] = a; ll.u[j] = b; }
    f.h[ks] = hh.v; f.l[ks] = ll.v;
  }
  return f;
}

// wave GEMM: D[16 rows][64 px] += W(h16 rows) * T, T px-row-major tile (rows=px, cols=c)
__device__ __forceinline__ void gemm_wave(const WFrag& w, const ushort* Th, const ushort* Tl,
                                          int lane, f32x4 acc[4]) {
  int m = lane & 15, q = lane >> 4;
#pragma unroll
  for (int nt = 0; nt < 4; nt++) {
#pragma unroll
    for (int ks = 0; ks < 2; ks++) {
      bf16x8 bh = ld8(Th, nt * 16 + m, ks * 4 + q);
      bf16x8 bl = ld8(Tl, nt * 16 + m, ks * 4 + q);
      acc[nt] = __builtin_amdgcn_mfma_f32_16x16x32_bf16(w.h[ks], bh, acc[nt], 0, 0, 0);
      acc[nt] = __builtin_amdgcn_mfma_f32_16x16x32_bf16(w.h[ks], bl, acc[nt], 0, 0, 0);
      acc[nt] = __builtin_amdgcn_mfma_f32_16x16x32_bf16(w.l[ks], bh, acc[nt], 0, 0, 0);
    }
  }
}

__device__ __forceinline__ void bilin_params(float py, float px, float w[4], int a[4]) {
  float y0f = floorf(py), x0f = floorf(px);
  float wy1 = py - y0f, wy0 = 1.f - wy1;
  float wx1 = px - x0f, wx0 = 1.f - wx1;
  int iy0 = (int)y0f, ix0 = (int)x0f;
  int iy1 = iy0 + 1, ix1 = ix0 + 1;
  float vy0 = (iy0 >= 0 && iy0 < HH) ? 1.f : 0.f;
  float vy1 = (iy1 >= 0 && iy1 < HH) ? 1.f : 0.f;
  float vx0 = (ix0 >= 0 && ix0 < WW) ? 1.f : 0.f;
  float vx1 = (ix1 >= 0 && ix1 < WW) ? 1.f : 0.f;
  int cy0 = min(max(iy0, 0), HH - 1), cy1 = min(max(iy1, 0), HH - 1);
  int cx0 = min(max(ix0, 0), WW - 1), cx1 = min(max(ix1, 0), WW - 1);
  w[0] = wy0 * wx0 * vy0 * vx0;
  w[1] = wy0 * wx1 * vy0 * vx1;
  w[2] = wy1 * wx0 * vy1 * vx0;
  w[3] = wy1 * wx1 * vy1 * vx1;
  a[0] = cy0 * WW + cx0;  a[1] = cy0 * WW + cx1;
  a[2] = cy1 * WW + cx0;  a[3] = cy1 * WW + cx1;
}

// sample 16 channels (this wave's block) of pixel `pix`, write bf16 hi/lo to px-row tile
__device__ __forceinline__ void sample16(const float* __restrict__ Xb,
                                         const float* __restrict__ pw,
                                         const int* __restrict__ pa,
                                         ushort* __restrict__ Sh, ushort* __restrict__ Sl,
                                         int pix, int cg) {
  float w0 = pw[0 * 64 + pix], w1 = pw[1 * 64 + pix], w2 = pw[2 * 64 + pix], w3 = pw[3 * 64 + pix];
  int a0 = pa[0 * 64 + pix], a1 = pa[1 * 64 + pix], a2 = pa[2 * 64 + pix], a3 = pa[3 * 64 + pix];
#pragma unroll 2
  for (int half = 0; half < 2; half++) {
    B8 hh, ll;
#pragma unroll
    for (int j = 0; j < 8; j++) {
      const float* Xc = Xb + (size_t)(half * 8 + j) * SS;
      float v = w0 * Xc[a0] + w1 * Xc[a1] + w2 * Xc[a2] + w3 * Xc[a3];
      ushort a, b; split(v, a, b); hh.u[j] = a; ll.u[j] = b;
    }
    int idx = pix * 64 + ((((cg * 2 + half) ^ (pix & 7))) << 3);
    *reinterpret_cast<bf16x8*>(Sh + idx) = hh.v;
    *reinterpret_cast<bf16x8*>(Sl + idx) = ll.v;
  }
}

// ---------------- K1: context accumulation (one 64-px tile per block) ----------------
__global__ __launch_bounds__(256, 5) void k_context(
    const float* __restrict__ x,
    const float* __restrict__ kow, const float* __restrict__ kob,
    const float* __restrict__ kw,
    const float* __restrict__ vow, const float* __restrict__ vob,
    const float* __restrict__ vw,
    float* __restrict__ num, float* __restrict__ den) {
  __shared__ ushort Sh[4096], Sl[4096];   // sample tile (px-rows); later E tiles (chan-rows)
  __shared__ ushort Vh[4096], Vl[4096];   // V tiles (chan-rows); early alias: red/pws/pas
  float* red = (float*)Vh;                // [4][4][64] = 1024 f (4KB of Vh's 8KB)
  float* pws = (float*)Vl;                // [2][4][64] = 512 f
  int*   pas = (int*)Vl + 512;            // [2][4][64] = 512 i

  const int t = threadIdx.x;
  const int bp = ((blockIdx.x & 7) << 9) | (blockIdx.x >> 3);
  const int xt = bp & 3, yrow = (bp >> 2) & 255, n = bp >> 10;
  const int xb = xt * 64;
  const int s0 = yrow * WW + xb;
  const float* xn = x + (size_t)n * CI * SS;
  const int pix = t & 63;                 // lane
  const int cg = t >> 6;                  // wave = head
  const int cgu = __builtin_amdgcn_readfirstlane(cg);
  const int m = pix & 15, q = pix >> 4;
  const float* Xb = xn + (size_t)(cgu * 16) * SS;

  // A: offset partial dots (k and v)
  {
    const float* xc = Xb + s0 + pix;
    float p0 = 0, p1 = 0, p2 = 0, p3 = 0;
#pragma unroll 8
    for (int i = 0; i < 16; i++) {
      float xv = xc[(size_t)i * SS];
      p0 += kow[cgu * 16 + i] * xv;
      p1 += kow[64 + cgu * 16 + i] * xv;
      p2 += vow[cgu * 16 + i] * xv;
      p3 += vow[64 + cgu * 16 + i] * xv;
    }
    red[(0 * 4 + cg) * 64 + pix] = p0;
    red[(1 * 4 + cg) * 64 + pix] = p1;
    red[(2 * 4 + cg) * 64 + pix] = p2;
    red[(3 * 4 + cg) * 64 + pix] = p3;
  }
  __syncthreads();
  // A2: bilinear params (sel 0=k, 1=v)
  if (t < 128) {
    int p = t & 63, sel = t >> 6, qb = sel * 2;
    float oy = red[((qb + 0) * 4 + 0) * 64 + p] + red[((qb + 0) * 4 + 1) * 64 + p] +
               red[((qb + 0) * 4 + 2) * 64 + p] + red[((qb + 0) * 4 + 3) * 64 + p];
    float ox = red[((qb + 1) * 4 + 0) * 64 + p] + red[((qb + 1) * 4 + 1) * 64 + p] +
               red[((qb + 1) * 4 + 2) * 64 + p] + red[((qb + 1) * 4 + 3) * 64 + p];
    const float* ob = sel ? vob : kob;
    float py = (float)yrow + oy + ob[0];
    float px = (float)(xb + p) + ox + ob[1];
    float w4[4]; int a4[4];
    bilin_params(py, px, w4, a4);
#pragma unroll
    for (int qq = 0; qq < 4; qq++) { pws[(sel * 4 + qq) * 64 + p] = w4[qq]; pas[(sel * 4 + qq) * 64 + p] = a4[qq]; }
  }
  __syncthreads();
  // C: sample k -> S
  sample16(Xb, pws, pas, Sh, Sl, pix, cg);
  WFrag wk = load_w(kw, cgu * 16, pix);
  __syncthreads();
  // D: keys GEMM (MFMA) -> exp -> den
  float ek[16];
  {
    f32x4 acc[4] = {{0,0,0,0},{0,0,0,0},{0,0,0,0},{0,0,0,0}};
    gemm_wave(wk, Sh, Sl, pix, acc);
#pragma unroll
    for (int nt = 0; nt < 4; nt++)
#pragma unroll
      for (int r = 0; r < 4; r++) ek[nt * 4 + r] = __expf(acc[nt][r]);
    float s[4];
#pragma unroll
    for (int r = 0; r < 4; r++) s[r] = ek[r] + ek[4 + r] + ek[8 + r] + ek[12 + r];
#pragma unroll
    for (int mask = 1; mask < 16; mask <<= 1)
#pragma unroll
      for (int r = 0; r < 4; r++) s[r] += __shfl_xor(s[r], mask);
    if (m == 0) {
#pragma unroll
      for (int r = 0; r < 4; r++) atomicAdd(&den[n * 64 + cgu * 16 + q * 4 + r], s[r]);
    }
  }
  __syncthreads();   // all S reads done
  // E: sample v -> S (overwrite)
  sample16(Xb, pws + 4 * 64, pas + 4 * 64, Sh, Sl, pix, cg);
  WFrag wv = load_w(vw, cgu * 16, pix);
  __syncthreads();
  // F: values GEMM (MFMA)
  f32x4 vacc[4] = {{0,0,0,0},{0,0,0,0},{0,0,0,0},{0,0,0,0}};
  gemm_wave(wv, Sh, Sl, pix, vacc);
  __syncthreads();   // S reads done; red/pws/pas dead
  // F2: commit E -> S-area, V -> V-area (chan-row tiles, hi/lo)
#pragma unroll
  for (int nt = 0; nt < 4; nt++) {
    int px = nt * 16 + m;
#pragma unroll
    for (int r = 0; r < 4; r++) {
      int row = cgu * 16 + q * 4 + r;
      int ix = swi(row, px);
      ushort a, b;
      split(ek[nt * 4 + r], a, b);  Sh[ix] = a; Sl[ix] = b;
      split(vacc[nt][r], a, b);     Vh[ix] = a; Vl[ix] = b;
    }
  }
  __syncthreads();
  // G: ctx = E * V^T per head via MFMA (A=E chan-rows, B=V chan-rows; k = px)
  {
    f32x4 c = {0, 0, 0, 0};
#pragma unroll
    for (int ks = 0; ks < 2; ks++) {
      bf16x8 ah = ld8(Sh, cgu * 16 + m, ks * 4 + q);
      bf16x8 al = ld8(Sl, cgu * 16 + m, ks * 4 + q);
      bf16x8 bh = ld8(Vh, cgu * 16 + m, ks * 4 + q);
      bf16x8 bl = ld8(Vl, cgu * 16 + m, ks * 4 + q);
      c = __builtin_amdgcn_mfma_f32_16x16x32_bf16(ah, bh, c, 0, 0, 0);
      c = __builtin_amdgcn_mfma_f32_16x16x32_bf16(ah, bl, c, 0, 0, 0);
      c = __builtin_amdgcn_mfma_f32_16x16x32_bf16(al, bh, c, 0, 0, 0);
    }
    float* nb = num + n * 1024 + cgu * 256;
#pragma unroll
    for (int r = 0; r < 4; r++) atomicAdd(&nb[(q * 4 + r) * 16 + m], c[r]);
  }
}

// ---------------- K3: query path + output ----------------
__global__ __launch_bounds__(256, 6) void k_output(
    const float* __restrict__ x,
    const float* __restrict__ qow, const float* __restrict__ qob,
    const float* __restrict__ qw,
    const float* __restrict__ rw, const float* __restrict__ rb,
    const float* __restrict__ num, const float* __restrict__ den,
    float* __restrict__ out) {
  __shared__ ushort Sh[4096], Sl[4096];   // q-sample -> qsmT -> att (all px-row tiles)
  __shared__ float ctxs[1024];
  __shared__ float pws2[256];
  __shared__ int   pas2[256];
  float* red2 = (float*)Sh;               // [8][64] = 512 f, dead before C

  const int t = threadIdx.x;
  const int bp = ((blockIdx.x & 7) << 9) | (blockIdx.x >> 3);
  const int xt = bp & 3, yrow = (bp >> 2) & 255, n = bp >> 10;
  const int xb = xt * 64;
  const int s0 = yrow * WW + xb;
  const float* xn = x + (size_t)n * CI * SS;
  const int pix = t & 63;
  const int cg = t >> 6;
  const int cgu = __builtin_amdgcn_readfirstlane(cg);
  const int m = pix & 15, q = pix >> 4;
  const float* Xb = xn + (size_t)(cgu * 16) * SS;

  // ctx normalize (used in E; ordered by barriers)
#pragma unroll
  for (int i = 0; i < 4; i++) {
    int e = t + i * 256;
    ctxs[e] = num[n * 1024 + e] / den[n * 64 + (e >> 4)];
  }

  // A: q offset partial dots -> red2 (rows cg, 4+cg)
  {
    const float* xc = Xb + s0 + pix;
    float p0 = 0, p1 = 0;
#pragma unroll 8
    for (int i = 0; i < 16; i++) {
      float xv = xc[(size_t)i * SS];
      p0 += qow[cgu * 16 + i] * xv;
      p1 += qow[64 + cgu * 16 + i] * xv;
    }
    red2[cg * 64 + pix] = p0;
    red2[(4 + cg) * 64 + pix] = p1;
  }
  __syncthreads();
  // A2
  if (t < 64) {
    float oy = red2[0 * 64 + t] + red2[1 * 64 + t] + red2[2 * 64 + t] + red2[3 * 64 + t];
    float ox = red2[4 * 64 + t] + red2[5 * 64 + t] + red2[6 * 64 + t] + red2[7 * 64 + t];
    float py = (float)yrow + oy + qob[0];
    float px = (float)(xb + t) + ox + qob[1];
    float w4[4]; int a4[4];
    bilin_params(py, px, w4, a4);
#pragma unroll
    for (int qq = 0; qq < 4; qq++) { pws2[qq * 64 + t] = w4[qq]; pas2[qq * 64 + t] = a4[qq]; }
  }
  __syncthreads();
  // C: sample q -> S (overwrites red2)
  sample16(Xb, pws2, pas2, Sh, Sl, pix, cg);
  WFrag wq = load_w(qw, cgu * 16, pix);
  __syncthreads();
  // D: queries GEMM (MFMA) + per-(px,head) softmax over 16 channels, in regs
  float qsm[16];
  {
    f32x4 acc[4] = {{0,0,0,0},{0,0,0,0},{0,0,0,0},{0,0,0,0}};
    gemm_wave(wq, Sh, Sl, pix, acc);
#pragma unroll
    for (int nt = 0; nt < 4; nt++) {
      float mx = fmaxf(fmaxf(acc[nt][0], acc[nt][1]), fmaxf(acc[nt][2], acc[nt][3]));
      mx = fmaxf(mx, __shfl_xor(mx, 16));
      mx = fmaxf(mx, __shfl_xor(mx, 32));
      float e[4]; float ssum = 0.f;
#pragma unroll
      for (int r = 0; r < 4; r++) { e[r] = __expf(acc[nt][r] - mx); ssum += e[r]; }
      ssum += __shfl_xor(ssum, 16);
      ssum += __shfl_xor(ssum, 32);
      float inv = 1.f / ssum;
#pragma unroll
      for (int r = 0; r < 4; r++) qsm[nt * 4 + r] = e[r] * inv;
    }
  }
  __syncthreads();   // S reads done
  // D2: write qsm^T -> S (px-row tile, col = h*16 + kdim)
#pragma unroll
  for (int nt = 0; nt < 4; nt++) {
    int px = nt * 16 + m;
#pragma unroll
    for (int r = 0; r < 4; r++) {
      int ix = swi(px, cgu * 16 + q * 4 + r);
      ushort a, b; split(qsm[nt * 4 + r], a, b);
      Sh[ix] = a; Sl[ix] = b;
    }
  }
  __syncthreads();
  // E: attended = ctx^T (A, K-padded to 32) x qsm (B) per head
  f32x4 att[4];
  {
    bf16x8 ah, al;
    B8 hh, ll;
#pragma unroll
    for (int j = 0; j < 8; j++) {
      float cv = (q < 2) ? ctxs[cgu * 256 + (q * 8 + j) * 16 + m] : 0.f;
      ushort a, b; split(cv, a, b); hh.u[j] = a; ll.u[j] = b;
    }
    ah = hh.v; al = ll.v;
    bf16x8 z = {0, 0, 0, 0, 0, 0, 0, 0};
#pragma unroll
    for (int nt = 0; nt < 4; nt++) {
      bf16x8 bh = (q < 2) ? ld8(Sh, nt * 16 + m, cgu * 2 + q) : z;
      bf16x8 bl = (q < 2) ? ld8(Sl, nt * 16 + m, cgu * 2 + q) : z;
      f32x4 c = {0, 0, 0, 0};
      c = __builtin_amdgcn_mfma_f32_16x16x32_bf16(ah, bh, c, 0, 0, 0);
      c = __builtin_amdgcn_mfma_f32_16x16x32_bf16(ah, bl, c, 0, 0, 0);
      c = __builtin_amdgcn_mfma_f32_16x16x32_bf16(al, bh, c, 0, 0, 0);
      att[nt] = c;
    }
  }
  __syncthreads();   // S reads done
  // E2: write att -> S (px-row tile, col = h*16 + vdim)
#pragma unroll
  for (int nt = 0; nt < 4; nt++) {
    int px = nt * 16 + m;
#pragma unroll
    for (int r = 0; r < 4; r++) {
      int ix = swi(px, cgu * 16 + q * 4 + r);
      ushort a, b; split(att[nt][r], a, b);
      Sh[ix] = a; Sl[ix] = b;
    }
  }
  WFrag wr = load_w(rw, cgu * 16, pix);
  float rbv[4];
#pragma unroll
  for (int r = 0; r < 4; r++) rbv[r] = rb[cgu * 16 + q * 4 + r];
  __syncthreads();
  // F: output GEMM + bias, store
  {
    f32x4 oacc[4] = {{0,0,0,0},{0,0,0,0},{0,0,0,0},{0,0,0,0}};
    gemm_wave(wr, Sh, Sl, pix, oacc);
#pragma unroll
    for (int nt = 0; nt < 4; nt++) {
#pragma unroll
      for (int r = 0; r < 4; r++) {
        int o = cgu * 16 + q * 4 + r;
        out[(size_t)(n * 64 + o) * SS + s0 + nt * 16 + m] = oacc[nt][r] + rbv[r];
      }
    }
  }
}

extern "C" void kernel_launch(void* const* d_in, const int* in_sizes, int n_in,
                              void* d_out, int out_size, void* d_ws, size_t ws_size,
                              hipStream_t stream) {
  const float* x   = (const float*)d_in[0];
  const float* kow = (const float*)d_in[1];
  const float* kob = (const float*)d_in[2];
  const float* kw  = (const float*)d_in[3];
  const float* qow = (const float*)d_in[4];
  const float* qob = (const float*)d_in[5];
  const float* qw  = (const float*)d_in[6];
  const float* vow = (const float*)d_in[7];
  const float* vob = (const float*)d_in[8];
  const float* vw  = (const float*)d_in[9];
  const float* rw  = (const float*)d_in[10];
  const float* rb  = (const float*)d_in[11];
  float* out = (float*)d_out;
  float* wsf = (float*)d_ws;
  float* num = wsf;          // 4096
  float* den = wsf + 4096;   // 256

  hipLaunchKernelGGL(k_zero, dim3(17), dim3(256), 0, stream, wsf);
  hipLaunchKernelGGL(k_context, dim3(4096), dim3(256), 0, stream,
                     x, kow, kob, kw, vow, vob, vw, num, den);
  hipLaunchKernelGGL(k_output, dim3(4096), dim3(256), 0, stream,
                     x, qow, qob, qw, rw, rb, num, den, out);
}